// Round 11
// baseline (258.820 us; speedup 1.0000x reference)
//
#include <hip/hip_runtime.h>
#include <math.h>

#define BB 4
#define LL 2048
#define DD 1024
#define HH 16
#define HD 64
#define BL (BB*LL)

typedef __attribute__((ext_vector_type(8))) short bf16x8;
typedef __attribute__((ext_vector_type(4))) short bf16x4;
typedef __attribute__((ext_vector_type(4))) float f32x4;

__device__ inline short f2bf(float f) {
    union { float f; unsigned u; } v; v.f = f;
    unsigned r = v.u + 0x7fffu + ((v.u >> 16) & 1u);   // RNE
    return (short)(r >> 16);
}

// pack two fp32 -> two bf16 (truncation; p>=0 so bias is benign, ~2^-9 rel)
// single v_perm_b32: D = {b.b3, b.b2, a.b3, a.b2}
__device__ inline unsigned pk_bf16(float a, float b) {
    union { float f; unsigned u; } x, y; x.f = a; y.f = b;
#if __has_builtin(__builtin_amdgcn_perm)
    return __builtin_amdgcn_perm(y.u, x.u, 0x07060302u);
#else
    return (x.u >> 16) | (y.u & 0xffff0000u);
#endif
}

__device__ inline float exp2x(float x) {
#if __has_builtin(__builtin_amdgcn_exp2f)
    return __builtin_amdgcn_exp2f(x);
#else
    return exp2f(x);
#endif
}

__device__ inline void gload_lds16(const void* g, void* l) {
    __builtin_amdgcn_global_load_lds(
        (const __attribute__((address_space(1))) unsigned int*)g,
        (__attribute__((address_space(3))) unsigned int*)l, 16, 0, 0);
}

// ---------------------------------------------------------------------------
// Fused prep kernel — rope table + x cast + 4-weight cast in ONE launch.
// Block ranges: [0,4096) x-cast, [4096,6144) weight cast4, [6144,6400) rope.
// ---------------------------------------------------------------------------
#define NB_CASTX ((BL*DD)/2048)         // 4096
#define NB_CASTW (4*((DD*DD)/2048))     // 2048
#define NB_ROPE  256

__global__ __launch_bounds__(256) void prep_kernel(
    const float* __restrict__ x,
    const float* __restrict__ w0, const float* __restrict__ w1,
    const float* __restrict__ w2, const float* __restrict__ w3,
    short* __restrict__ xb, short* __restrict__ wout,
    float2* __restrict__ tab)
{
    const int bid = blockIdx.x;
    if (bid < NB_CASTX) {
        int i = (bid * 256 + threadIdx.x) * 8;
        float4 a = *(const float4*)(x + i);
        float4 b = *(const float4*)(x + i + 4);
        bf16x8 o;
        o[0]=f2bf(a.x); o[1]=f2bf(a.y); o[2]=f2bf(a.z); o[3]=f2bf(a.w);
        o[4]=f2bf(b.x); o[5]=f2bf(b.y); o[6]=f2bf(b.z); o[7]=f2bf(b.w);
        *(bf16x8*)(xb + i) = o;
    } else if (bid < NB_CASTX + NB_CASTW) {
        const int nw_blocks = (DD*DD) / 2048;    // 512
        int b2  = bid - NB_CASTX;
        int sel = b2 / nw_blocks;
        int blk = b2 % nw_blocks;
        const float* in = (sel == 0) ? w0 : (sel == 1) ? w1 : (sel == 2) ? w2 : w3;
        int i = (blk * 256 + threadIdx.x) * 8;
        float4 a = *(const float4*)(in + i);
        float4 b = *(const float4*)(in + i + 4);
        bf16x8 o;
        o[0]=f2bf(a.x); o[1]=f2bf(a.y); o[2]=f2bf(a.z); o[3]=f2bf(a.w);
        o[4]=f2bf(b.x); o[5]=f2bf(b.y); o[6]=f2bf(b.z); o[7]=f2bf(b.w);
        *(bf16x8*)(wout + (size_t)sel * DD * DD + i) = o;
    } else {
        int idx = (bid - NB_CASTX - NB_CASTW) * 256 + threadIdx.x;
        int lq = idx >> 5, f = idx & 31;
        float inv = __expf((float)f * (-9.210340371976184f / 32.0f));
        float s, c;
        sincosf((float)lq * inv, &s, &c);
        tab[idx] = make_float2(c, s);
    }
}

// ---------------------------------------------------------------------------
// R17: 256x128-tile phase-split GEMM (512 threads, 8 waves as 4M x 2N,
// per-wave 64x64 output, BK=64, 96 KB LDS double-buffer).
// Per K-tile: 2 phases of {ds_read frags || issue prefetch -> s_barrier ->
// setprio(1) + 16 MFMA + setprio(0) -> s_barrier}; A(next) issued in phase 0
// (its buffer's reads finished a full tile earlier), B(next) in phase 1
// (its buffer free since prev tile's phase 0); single own-wave vmcnt(0) at
// tile end — by then loads had ~2 phases to land (L2 ~200cy).
// Mechanisms vs the 128^2 2-phase form: 2x arithmetic intensity (85 vs 64
// FLOP per staged byte), setprio now has wave role-diversity to arbitrate,
// T2 granule-XOR swizzle carried over (pre-swizzled global source + linear
// gload_lds dest + XOR'd read; conflicts stay ~0).
// ---------------------------------------------------------------------------
__device__ inline void gemm256(const short* __restrict__ A,
                               const short* __restrict__ B,
                               short* S,   // 49152 shorts = 96 KB
                               int i0, int n0, f32x4 (&acc)[4][4])
{
    const int t   = threadIdx.x;
    const int wid = t >> 6;
    const int wr  = wid >> 1;        // 0..3 (M)
    const int wc  = wid & 1;         // 0..1 (N)
    const int l   = t & 63;
    const int g   = (l >> 4) & 3;
    const int ln  = l & 15;
    const int rsw = 8 * (ln & 7);    // read-side XOR key (row&7 == ln&7)

    short* A0 = S;                   // 16384 shorts each
    short* A1 = S + 16384;
    short* B0 = S + 32768;           // 8192 shorts each
    short* B1 = S + 40960;

    const int srow = t >> 3;                       // 0..63 per issue
    const int sgr  = ((t & 7) ^ (srow & 7)) * 8;   // source granule pre-swizzle
    const short* gA = A + (size_t)(i0 + srow) * DD + sgr;
    const short* gB = B + (size_t)(n0 + srow) * DD + sgr;
    const int lofs = wid * 512;      // wave-uniform LDS chunk

    // prologue: stage K-tile 0
    {
        short* la = A0 + lofs; short* lb = B0 + lofs;
        gload_lds16(gA,          la);
        gload_lds16(gA +  64*DD, la + 4096);
        gload_lds16(gA + 128*DD, la + 8192);
        gload_lds16(gA + 192*DD, la + 12288);
        gload_lds16(gB,          lb);
        gload_lds16(gB +  64*DD, lb + 4096);
    }
    asm volatile("s_waitcnt vmcnt(0)" ::: "memory");
    __builtin_amdgcn_s_barrier();

    const int arow = wr*64 + ln;     // + mi*16
    const int brow = wc*64 + ln;     // + nj*16

    for (int k0 = 0; k0 < DD; k0 += 64) {
        short* Ab = (k0 & 64) ? A1 : A0;
        short* Bb = (k0 & 64) ? B1 : B0;
        short* An = (k0 & 64) ? A0 : A1;
        short* Bn = (k0 & 64) ? B0 : B1;
        const bool pf = (k0 + 64 < DD);

        // ---- phase 0: all B-frags + A-frags mi=0,1 ; prefetch A(next) ----
        bf16x8 bfr[4][2], af0[2][2];
        #pragma unroll
        for (int nj = 0; nj < 4; ++nj)
            #pragma unroll
            for (int kk = 0; kk < 2; ++kk)
                bfr[nj][kk] = *(const bf16x8*)(Bb + (brow + nj*16)*64 + ((kk*32 + 8*g) ^ rsw));
        #pragma unroll
        for (int mi = 0; mi < 2; ++mi)
            #pragma unroll
            for (int kk = 0; kk < 2; ++kk)
                af0[mi][kk] = *(const bf16x8*)(Ab + (arow + mi*16)*64 + ((kk*32 + 8*g) ^ rsw));
        if (pf) {
            const short* ga = gA + k0 + 64;
            short* la = An + lofs;
            gload_lds16(ga,          la);
            gload_lds16(ga +  64*DD, la + 4096);
            gload_lds16(ga + 128*DD, la + 8192);
            gload_lds16(ga + 192*DD, la + 12288);
        }
        __builtin_amdgcn_s_barrier();
        __builtin_amdgcn_s_setprio(1);
        #pragma unroll
        for (int mi = 0; mi < 2; ++mi)
            #pragma unroll
            for (int nj = 0; nj < 4; ++nj) {
                acc[mi][nj] = __builtin_amdgcn_mfma_f32_16x16x32_bf16(af0[mi][0], bfr[nj][0], acc[mi][nj], 0, 0, 0);
                acc[mi][nj] = __builtin_amdgcn_mfma_f32_16x16x32_bf16(af0[mi][1], bfr[nj][1], acc[mi][nj], 0, 0, 0);
            }
        __builtin_amdgcn_s_setprio(0);
        __builtin_amdgcn_s_barrier();

        // ---- phase 1: A-frags mi=2,3 ; prefetch B(next) ----
        bf16x8 af1[2][2];
        #pragma unroll
        for (int mi = 0; mi < 2; ++mi)
            #pragma unroll
            for (int kk = 0; kk < 2; ++kk)
                af1[mi][kk] = *(const bf16x8*)(Ab + (arow + (mi+2)*16)*64 + ((kk*32 + 8*g) ^ rsw));
        if (pf) {
            const short* gb = gB + k0 + 64;
            short* lb = Bn + lofs;
            gload_lds16(gb,         lb);
            gload_lds16(gb + 64*DD, lb + 4096);
        }
        __builtin_amdgcn_s_barrier();
        __builtin_amdgcn_s_setprio(1);
        #pragma unroll
        for (int mi = 0; mi < 2; ++mi)
            #pragma unroll
            for (int nj = 0; nj < 4; ++nj) {
                acc[mi+2][nj] = __builtin_amdgcn_mfma_f32_16x16x32_bf16(af1[mi][0], bfr[nj][0], acc[mi+2][nj], 0, 0, 0);
                acc[mi+2][nj] = __builtin_amdgcn_mfma_f32_16x16x32_bf16(af1[mi][1], bfr[nj][1], acc[mi+2][nj], 0, 0, 0);
            }
        __builtin_amdgcn_s_setprio(0);
        if (pf) asm volatile("s_waitcnt vmcnt(0)" ::: "memory");
        __builtin_amdgcn_s_barrier();
    }
}

// ---------------------------------------------------------------------------
// Kernel 1: QKV projection + RoPE. 512 threads, grid 768 (= 3 CU-rounds).
// XCD decode: r8 = gid&7 owns i-tiles r8*4..r8*4+3 (1 MB of x per XCD L2);
// u iterates 4 i-low x 8 n x 3 z. Per-wave output = 64 tokens x one head.
// z=0/1: Q/K roped via table, Q scaled 0.125*log2(e), layout (B,H,L,Hd).
// K stored with 16-B-granule columns XOR-swizzled by token&7 (rule #21 —
// attn stages it with linear global_load_lds and reads conflict-free).
// z=2: V transposed (B,H,Hd,L) via LDS transpose (S reused as buf);
// keys bit-permuted within each 64-key tile + granule XOR swizzle by d&7.
// ---------------------------------------------------------------------------
__global__ __launch_bounds__(512, 2) void qkv_mfma_kernel(
    const short* __restrict__ xb, const short* __restrict__ Wqb,
    const short* __restrict__ Wkb, const short* __restrict__ Wvb,
    const float2* __restrict__ rope_tab,
    short* __restrict__ Qo, short* __restrict__ Ko, short* __restrict__ Vo)
{
    __shared__ short S[49152];   // 96 KB: A0|A1|B0|B1 (reused as V buf)

    const int gid = blockIdx.x;
    const int r8  = gid & 7;               // XCD slot
    const int u   = gid >> 3;              // 0..95
    const int i_idx = r8 * 4 + (u & 3);    // 0..31
    const int nz  = u >> 2;                // 0..23
    const int n_idx = nz & 7;              // 0..7
    const int z   = nz >> 3;               // 0..2

    const short* Wm = (z == 0) ? Wqb : ((z == 1) ? Wkb : Wvb);
    const int i0 = i_idx * 256;
    const int n0 = n_idx * 128;

    f32x4 acc[4][4];
    #pragma unroll
    for (int mi = 0; mi < 4; ++mi)
        #pragma unroll
        for (int nj = 0; nj < 4; ++nj) acc[mi][nj] = (f32x4){0.f,0.f,0.f,0.f};

    gemm256(xb, Wm, S, i0, n0, acc);

    const int t   = threadIdx.x;
    const int wid = t >> 6;
    const int wr  = wid >> 1;
    const int wc  = wid & 1;
    const int l   = t & 63;
    const int g   = (l >> 4) & 3;
    const int ln  = l & 15;

    if (z == 2) {
        // transpose via buf[64 d][264 token-stride]; one head per pass.
        short* buf = S;
        const int b = i0 >> 11, l0 = i0 & (LL - 1);
        const int d = t >> 3;          // 0..63
        const int c = t & 7;           // 0..7
        const int dk = d & 7;          // V granule swizzle key
        __syncthreads();
        #pragma unroll
        for (int hp = 0; hp < 2; ++hp) {
            __syncthreads();
            if (wc == hp) {            // waves owning head hp write their 64x64
                #pragma unroll
                for (int nj = 0; nj < 4; ++nj)
                    #pragma unroll
                    for (int mi = 0; mi < 4; ++mi)
                        #pragma unroll
                        for (int r = 0; r < 4; ++r)
                            buf[(nj*16 + ln)*264 + wr*64 + mi*16 + 4*g + r]
                                = f2bf(acc[mi][nj][r]);
            }
            __syncthreads();
            short* dst = Vo + ((size_t)((b*HH + n_idx*2 + hp)*HD + d)) * LL + l0;
            // src token s = c*8 + j*64 + off (off 0..7); 64-token tile tb=j;
            // s&63 = 32hb+16aa+8(c&1)+off -> hb=c>>2, aa=(c>>1)&1, g0=2(c&1);
            // key' granule = 2g + hb (g=g0 for lo, g0+1 for hi), XOR d&7.
            #pragma unroll
            for (int j = 0; j < 4; ++j) {
                const short* src = buf + d*264 + c*8 + j*64;
                bf16x4 lo = *(const bf16x4*)(src);
                bf16x4 hi = *(const bf16x4*)(src + 4);
                const int tb = j * 64;
                const int hb = c >> 2;
                const int aa = (c >> 1) & 1;
                const int g0 = (c & 1) * 2;
                const int gi1 = 2*g0 + hb;
                *(bf16x4*)(dst + tb + ((gi1     ^ dk) << 3) + aa*4) = lo;
                *(bf16x4*)(dst + tb + (((gi1+2) ^ dk) << 3) + aa*4) = hi;
            }
        }
    } else {
        const int h = n_idx * 2 + wc;
        short* Om = (z == 0) ? Qo : Ko;
        // Q: 1/sqrt(64) * log2(e) so scores feed exp2 directly
        const float sc = (z == 0) ? 0.180336880111112f : 1.0f;
        const int gi0 = ln >> 3;
        const int wi  = ln & 7;
        #pragma unroll
        for (int mi = 0; mi < 4; ++mi)
            #pragma unroll
            for (int r = 0; r < 4; ++r) {
                int i = i0 + wr*64 + mi*16 + 4*g + r;
                int b = i >> 11, lq = i & (LL - 1);
                float2 cs0 = rope_tab[lq*32 + ln];        // freq ln
                float2 cs1 = rope_tab[lq*32 + ln + 16];   // freq ln+16
                float r0 = (acc[mi][0][r]*cs0.x - acc[mi][2][r]*cs0.y) * sc;
                float r2 = (acc[mi][2][r]*cs0.x + acc[mi][0][r]*cs0.y) * sc;
                float r1 = (acc[mi][1][r]*cs1.x - acc[mi][3][r]*cs1.y) * sc;
                float r3 = (acc[mi][3][r]*cs1.x + acc[mi][1][r]*cs1.y) * sc;
                size_t base = ((size_t)(b*HH + h) * LL + lq) * HD;
                // K swizzled by lq&7 (== (4g+r)&7); Q linear (xk=0).
                int xk = (z == 0) ? 0 : ((4*g + r) & 7);
                Om[base + (((gi0    ) ^ xk) << 3) + wi] = f2bf(r0);  // col ln
                Om[base + (((gi0 + 2) ^ xk) << 3) + wi] = f2bf(r1);  // col ln+16
                Om[base + (((gi0 + 4) ^ xk) << 3) + wi] = f2bf(r2);  // col ln+32
                Om[base + (((gi0 + 6) ^ xk) << 3) + wi] = f2bf(r3);  // col ln+48
            }
    }
}

// ---------------------------------------------------------------------------
// Kernel 2: bf16 MFMA flash attention (unchanged from R15).
// grid = (B*H, L/128): bh on x => the 16 q-tile blocks sharing one bh get
// gid == bh (mod 8) -> same XCD -> K/V stay in one L2.
//  (a) l-sum via MFMA ones-trick (lsum element r == O row 4g+r).
//  (b) VT global layout key-bit-permuted -> PV B-frag = one granule read.
//  (c) pk_bf16 = single v_perm_b32.
//  (d) staging via global_load_lds (linear [64][64] LDS; K/VT pre-swizzled
//      in GLOBAL by qkv, reads XOR granule with ln&7).
// ---------------------------------------------------------------------------
__global__ __launch_bounds__(256) void attn_kernel(
    const short* __restrict__ Q, const short* __restrict__ K,
    const short* __restrict__ VT, short* __restrict__ AO)
{
    __shared__ short Ksh[64*64];   // [key][d-granule swizzled]
    __shared__ short VTs[64*64];   // [d][key'-granule swizzled]

    const int t  = threadIdx.x;
    const int w  = t >> 6;
    const int l  = t & 63;
    const int g  = l >> 4;
    const int ln = l & 15;

    const int bh = blockIdx.x;
    const int q0 = blockIdx.y * 128;
    const short* Qb  = Q  + ((size_t)bh * LL + q0 + w*32) * HD;
    const short* Kb  = K  + (size_t)bh * LL * HD;
    const short* VTb = VT + (size_t)bh * HD * LL;

    // Q B-frags: [n=q=ln][k=d=8g+j(+32)] (Q global layout is linear)
    bf16x8 qb[2][2];
    #pragma unroll
    for (int qi = 0; qi < 2; ++qi) {
        qb[qi][0] = *(const bf16x8*)(Qb + (size_t)(qi*16 + ln)*HD + 8*g);
        qb[qi][1] = *(const bf16x8*)(Qb + (size_t)(qi*16 + ln)*HD + 32 + 8*g);
    }

    const bf16x8 ONES = { (short)0x3F80, (short)0x3F80, (short)0x3F80, (short)0x3F80,
                          (short)0x3F80, (short)0x3F80, (short)0x3F80, (short)0x3F80 };

    f32x4 O[2][4];                 // O[qi][db]: row q=4g+r, col d=db*16+ln
    #pragma unroll
    for (int qi = 0; qi < 2; ++qi)
        #pragma unroll
        for (int db = 0; db < 4; ++db) O[qi][db] = (f32x4){0.f,0.f,0.f,0.f};
    f32x4 lsum[2];                 // lsum[qi][r] = l for row q=4g+r (any ln)
    lsum[0] = (f32x4){0.f,0.f,0.f,0.f};
    lsum[1] = (f32x4){0.f,0.f,0.f,0.f};

    // staging geometry: wave w copies rows [w*16, w*16+16) of each 64x64
    // tile; lane l -> row +(l>>3), granule l&7. LDS dest linear.
    const int srow = l >> 3;          // 0..7
    const int scol = (l & 7) * 8;     // granule col (shorts)
    short* kdst = Ksh + w*1024;       // wave-uniform
    short* vdst = VTs + w*1024;
    const int lx = ln & 7;            // read-side XOR key

    for (int kt = 0; kt < LL; kt += 64) {
        __syncthreads();           // previous tile fully consumed
        const short* gk = Kb  + (size_t)(kt + w*16 + srow)*HD + scol;
        const short* gv = VTb + (size_t)(w*16 + srow)*LL + kt + scol;
        gload_lds16(gk,        kdst);
        gload_lds16(gk + 8*HD, kdst + 512);
        gload_lds16(gv,        vdst);
        gload_lds16(gv + 8*LL, vdst + 512);
        __syncthreads();           // auto vmcnt(0) drain -> LDS ready

        unsigned pf[2][4][2];      // [qi][kb]: keys (4g,4g+1),(4g+2,4g+3)
        #pragma unroll
        for (int kb = 0; kb < 4; ++kb) {
            // K A-frags: [m=key=kb*16+ln][k=d], granules g and g+4, XOR lx
            bf16x8 ka0 = *(const bf16x8*)(Ksh + (kb*16 + ln)*64 + ((g       ^ lx) << 3));
            bf16x8 ka1 = *(const bf16x8*)(Ksh + (kb*16 + ln)*64 + (((g + 4) ^ lx) << 3));
            #pragma unroll
            for (int qi = 0; qi < 2; ++qi) {
                f32x4 Sv = (f32x4){0.f,0.f,0.f,0.f};
                Sv = __builtin_amdgcn_mfma_f32_16x16x32_bf16(ka0, qb[qi][0], Sv, 0, 0, 0);
                Sv = __builtin_amdgcn_mfma_f32_16x16x32_bf16(ka1, qb[qi][1], Sv, 0, 0, 0);
                float p0 = exp2x(Sv[0]), p1 = exp2x(Sv[1]);
                float p2 = exp2x(Sv[2]), p3 = exp2x(Sv[3]);
                pf[qi][kb][0] = pk_bf16(p0, p1);
                pf[qi][kb][1] = pk_bf16(p2, p3);
            }
        }

        // P A-frags for PV/lsum: slot (g,j) <-> key 32hb + 16*(j>>2) + 4g + (j&3)
        bf16x8 pa[2][2];
        #pragma unroll
        for (int qi = 0; qi < 2; ++qi)
            #pragma unroll
            for (int hb = 0; hb < 2; ++hb) {
                union { unsigned u[4]; bf16x8 v; } a;
                a.u[0] = pf[qi][2*hb][0];   a.u[1] = pf[qi][2*hb][1];
                a.u[2] = pf[qi][2*hb+1][0]; a.u[3] = pf[qi][2*hb+1][1];
                pa[qi][hb] = a.v;
            }

        // l-sum: one MFMA per (hb,qi) with all-ones B
        #pragma unroll
        for (int hb = 0; hb < 2; ++hb) {
            lsum[0] = __builtin_amdgcn_mfma_f32_16x16x32_bf16(pa[0][hb], ONES, lsum[0], 0, 0, 0);
            lsum[1] = __builtin_amdgcn_mfma_f32_16x16x32_bf16(pa[1][hb], ONES, lsum[1], 0, 0, 0);
        }

        // PV via 16x16x32: B-frag = granule (2g+hb) ^ lx of row db*16+ln
        #pragma unroll
        for (int hb = 0; hb < 2; ++hb) {
            #pragma unroll
            for (int db = 0; db < 4; ++db) {
                bf16x8 vf = *(const bf16x8*)(VTs + (db*16 + ln)*64 + (((2*g + hb) ^ lx) << 3));
                O[0][db] = __builtin_amdgcn_mfma_f32_16x16x32_bf16(pa[0][hb], vf, O[0][db], 0, 0, 0);
                O[1][db] = __builtin_amdgcn_mfma_f32_16x16x32_bf16(pa[1][hb], vf, O[1][db], 0, 0, 0);
            }
        }
    }

    // epilogue: lsum[qi][r] is exactly l for row q=4g+r — no shuffles.
    const int b = bh >> 4, h = bh & 15;
    #pragma unroll
    for (int qi = 0; qi < 2; ++qi) {
        #pragma unroll
        for (int r = 0; r < 4; ++r) {
            float inv = 1.0f / lsum[qi][r];
            int q = q0 + w*32 + qi*16 + 4*g + r;
            size_t base = ((size_t)(b*LL + q)) * DD + h*HD;
            #pragma unroll
            for (int db = 0; db < 4; ++db)
                AO[base + db*16 + ln] = f2bf(O[qi][db][r] * inv);
        }
    }
}

// ---------------------------------------------------------------------------
// Kernel 3: output projection. 512 threads, grid 256 (= exactly 1 CU-round),
// same 256x128 gemm core; fp32 direct store.
// ---------------------------------------------------------------------------
__global__ __launch_bounds__(512, 2) void oproj_mfma_kernel(
    const short* __restrict__ A, const short* __restrict__ Wob,
    float* __restrict__ out)
{
    __shared__ short S[49152];   // 96 KB

    const int gid = blockIdx.x;            // 0..255
    const int r8  = gid & 7;
    const int u   = gid >> 3;              // 0..31
    const int i_idx = r8 * 4 + (u & 3);    // 0..31
    const int n_idx = u >> 2;              // 0..7
    const int i0 = i_idx * 256;
    const int n0 = n_idx * 128;

    f32x4 acc[4][4];
    #pragma unroll
    for (int mi = 0; mi < 4; ++mi)
        #pragma unroll
        for (int nj = 0; nj < 4; ++nj) acc[mi][nj] = (f32x4){0.f,0.f,0.f,0.f};

    gemm256(A, Wob, S, i0, n0, acc);

    const int t   = threadIdx.x;
    const int wid = t >> 6;
    const int wr  = wid >> 1;
    const int wc  = wid & 1;
    const int l   = t & 63;
    const int g   = (l >> 4) & 3;
    const int ln  = l & 15;

    #pragma unroll
    for (int mi = 0; mi < 4; ++mi)
        #pragma unroll
        for (int r = 0; r < 4; ++r) {
            size_t base = (size_t)(i0 + wr*64 + mi*16 + 4*g + r) * DD + n0 + wc*64;
            #pragma unroll
            for (int nj = 0; nj < 4; ++nj)
                out[base + nj*16 + ln] = acc[mi][nj][r];
        }
}

// ---------------------------------------------------------------------------
extern "C" void kernel_launch(void* const* d_in, const int* in_sizes, int n_in,
                              void* d_out, int out_size, void* d_ws, size_t ws_size,
                              hipStream_t stream) {
    const float* x  = (const float*)d_in[0];
    const float* Wq = (const float*)d_in[1];
    const float* Wk = (const float*)d_in[2];
    const float* Wv = (const float*)d_in[3];
    const float* Wo = (const float*)d_in[4];
    float* out = (float*)d_out;

    const size_t n_x = (size_t)BL * DD;   // 8.4M
    const size_t n_w = (size_t)DD * DD;   // 1.05M
    short* xb  = (short*)d_ws;
    short* Wqb = xb  + n_x;               // Wqb..Wob contiguous (prep relies on it)
    short* Wkb = Wqb + n_w;
    short* Wvb = Wkb + n_w;
    short* Wob = Wvb + n_w;
    short* Q   = Wob + n_w;
    short* K   = Q   + n_x;               // granule-swizzled by token&7
    short* VTg = K   + n_x;               // V transposed, key-permuted + swizzled
    short* AOb = VTg + n_x;
    float2* tab = (float2*)(AOb + n_x);   // 65536 float2 = 512 KB

    prep_kernel<<<NB_CASTX + NB_CASTW + NB_ROPE, 256, 0, stream>>>(
        x, Wq, Wk, Wv, Wo, xb, Wqb, tab);

    qkv_mfma_kernel<<<768, 512, 0, stream>>>(xb, Wqb, Wkb, Wvb, tab, Q, K, VTg);

    dim3 g2(BB*HH, LL/128);
    attn_kernel<<<g2, 256, 0, stream>>>(Q, K, VTg, AOb);

    oproj_mfma_kernel<<<256, 512, 0, stream>>>(AOb, Wob, out);
}

// Round 13
// 242.675 us; speedup vs baseline: 1.0665x; 1.0665x over previous
//
#include <hip/hip_runtime.h>
#include <math.h>

#define BB 4
#define LL 2048
#define DD 1024
#define HH 16
#define HD 64
#define BL (BB*LL)

typedef __attribute__((ext_vector_type(8))) short bf16x8;
typedef __attribute__((ext_vector_type(4))) short bf16x4;
typedef __attribute__((ext_vector_type(4))) float f32x4;

__device__ inline short f2bf(float f) {
    union { float f; unsigned u; } v; v.f = f;
    unsigned r = v.u + 0x7fffu + ((v.u >> 16) & 1u);   // RNE
    return (short)(r >> 16);
}

// pack two fp32 -> two bf16 (truncation; p>=0 so bias is benign, ~2^-9 rel)
// single v_perm_b32: D = {b.b3, b.b2, a.b3, a.b2}
__device__ inline unsigned pk_bf16(float a, float b) {
    union { float f; unsigned u; } x, y; x.f = a; y.f = b;
#if __has_builtin(__builtin_amdgcn_perm)
    return __builtin_amdgcn_perm(y.u, x.u, 0x07060302u);
#else
    return (x.u >> 16) | (y.u & 0xffff0000u);
#endif
}

__device__ inline float exp2x(float x) {
#if __has_builtin(__builtin_amdgcn_exp2f)
    return __builtin_amdgcn_exp2f(x);
#else
    return exp2f(x);
#endif
}

__device__ inline void gload_lds16(const void* g, void* l) {
    __builtin_amdgcn_global_load_lds(
        (const __attribute__((address_space(1))) unsigned int*)g,
        (__attribute__((address_space(3))) unsigned int*)l, 16, 0, 0);
}

// ---------------------------------------------------------------------------
// Fused prep kernel — rope table + x cast + 4-weight cast in ONE launch.
// Block ranges: [0,4096) x-cast, [4096,6144) weight cast4, [6144,6400) rope.
// ---------------------------------------------------------------------------
#define NB_CASTX ((BL*DD)/2048)         // 4096
#define NB_CASTW (4*((DD*DD)/2048))     // 2048
#define NB_ROPE  256

__global__ __launch_bounds__(256) void prep_kernel(
    const float* __restrict__ x,
    const float* __restrict__ w0, const float* __restrict__ w1,
    const float* __restrict__ w2, const float* __restrict__ w3,
    short* __restrict__ xb, short* __restrict__ wout,
    float2* __restrict__ tab)
{
    const int bid = blockIdx.x;
    if (bid < NB_CASTX) {
        int i = (bid * 256 + threadIdx.x) * 8;
        float4 a = *(const float4*)(x + i);
        float4 b = *(const float4*)(x + i + 4);
        bf16x8 o;
        o[0]=f2bf(a.x); o[1]=f2bf(a.y); o[2]=f2bf(a.z); o[3]=f2bf(a.w);
        o[4]=f2bf(b.x); o[5]=f2bf(b.y); o[6]=f2bf(b.z); o[7]=f2bf(b.w);
        *(bf16x8*)(xb + i) = o;
    } else if (bid < NB_CASTX + NB_CASTW) {
        const int nw_blocks = (DD*DD) / 2048;    // 512
        int b2  = bid - NB_CASTX;
        int sel = b2 / nw_blocks;
        int blk = b2 % nw_blocks;
        const float* in = (sel == 0) ? w0 : (sel == 1) ? w1 : (sel == 2) ? w2 : w3;
        int i = (blk * 256 + threadIdx.x) * 8;
        float4 a = *(const float4*)(in + i);
        float4 b = *(const float4*)(in + i + 4);
        bf16x8 o;
        o[0]=f2bf(a.x); o[1]=f2bf(a.y); o[2]=f2bf(a.z); o[3]=f2bf(a.w);
        o[4]=f2bf(b.x); o[5]=f2bf(b.y); o[6]=f2bf(b.z); o[7]=f2bf(b.w);
        *(bf16x8*)(wout + (size_t)sel * DD * DD + i) = o;
    } else {
        int idx = (bid - NB_CASTX - NB_CASTW) * 256 + threadIdx.x;
        int lq = idx >> 5, f = idx & 31;
        float inv = __expf((float)f * (-9.210340371976184f / 32.0f));
        float s, c;
        sincosf((float)lq * inv, &s, &c);
        tab[idx] = make_float2(c, s);
    }
}

// ---------------------------------------------------------------------------
// Shared 128x128-tile bf16 MFMA K-loop (m97 2-barrier structure, 32 KB LDS).
// XOR-swizzled LDS columns (rule #21: linear gload_lds dest + pre-swizzled
// GLOBAL source + swizzled read) — conflicts 1.9e7 -> 2.6e5. Callers pin
// __launch_bounds__(256,4) => 128-reg cap (132 crossed the occupancy cliff).
// NOTE (session ledger): this 2-phase structure's ceiling was probed four
// ways — 64KB dbuf (R10, -17% residency), BK=32 dbuf (R16, neutral:
// drain-0 pipeline ~= none), 256x128 phase-split (R17, neutral: same),
// counted-vmcnt 3-stage (R18, RACED). Counted vmcnt across barriers is the
// only lever that breaks it and it requires race-screen infra not present.
// ---------------------------------------------------------------------------
__device__ inline void gemm_bt_128(const short* __restrict__ A,
                                   const short* __restrict__ B,
                                   short* Ash, short* Bsh,
                                   int i0, int n0, f32x4 (&acc)[4][4])
{
    const int t  = threadIdx.x;
    const int w  = t >> 6;
    const int l  = t & 63;
    const int g  = (t >> 4) & 3;
    const int ln = t & 15;
    const int rh = (w >> 1) * 64;
    const int ch = (w & 1) * 64;
    const int srow = w * 8 + (l >> 3);
    const int skol = ((l & 7) ^ (l >> 3)) * 8;   // source col swizzled by row&7
    const int rsw  = 8 * (ln & 7);               // read-side XOR key (row&7 == ln&7)

    for (int k0 = 0; k0 < DD; k0 += 64) {
        __syncthreads();
        const short* ga = A + (size_t)(i0 + srow) * DD + k0 + skol;
        const short* gb = B + (size_t)(n0 + srow) * DD + k0 + skol;
        short* la = Ash + w * 512;   // wave-uniform base
        short* lb = Bsh + w * 512;
        #pragma unroll
        for (int j = 0; j < 4; ++j) {
            gload_lds16(ga + j * 32 * DD, la + j * 2048);
            gload_lds16(gb + j * 32 * DD, lb + j * 2048);
        }
        __syncthreads();

        #pragma unroll
        for (int kk = 0; kk < 2; ++kk) {
            bf16x8 af[4], bfr[4];
            #pragma unroll
            for (int mi = 0; mi < 4; ++mi)
                af[mi] = *(const bf16x8*)(Ash + (rh + mi*16 + ln)*64 + ((kk*32 + 8*g) ^ rsw));
            #pragma unroll
            for (int nj = 0; nj < 4; ++nj)
                bfr[nj] = *(const bf16x8*)(Bsh + (ch + nj*16 + ln)*64 + ((kk*32 + 8*g) ^ rsw));
            #pragma unroll
            for (int mi = 0; mi < 4; ++mi)
                #pragma unroll
                for (int nj = 0; nj < 4; ++nj)
                    acc[mi][nj] = __builtin_amdgcn_mfma_f32_16x16x32_bf16(
                        af[mi], bfr[nj], acc[mi][nj], 0, 0, 0);
        }
    }
}

// ---------------------------------------------------------------------------
// Kernel 1: QKV projection + RoPE. 1-D grid 1536, XCD-aware decode:
// xcd r = gid&7 owns i-tiles r*8..r*8+7 (2 MB of x stays in that XCD's L2)
// and iterates all 24 (n,z) W-tiles (W-tile reused back-to-back).
// z=0/1: Q/K roped via table, Q scaled 0.125*log2(e), layout (B,H,L,Hd).
// K is stored with 16-B-granule columns XOR-swizzled by token&7 so attn can
// stage it with linear global_load_lds and read conflict-free (rule #21).
// Q stays linear (attn reads Q directly from global).
// z=2: V transposed (B,H,Hd,L) via two-pass LDS transpose; keys are
// bit-permuted within each 64-key tile (key' [5:4]=g,[3]=hb,[2]=a,[1:0]=r)
// plus the same granule XOR swizzle by d&7.
// ---------------------------------------------------------------------------
__global__ __launch_bounds__(256, 4) void qkv_mfma_kernel(
    const short* __restrict__ xb, const short* __restrict__ Wqb,
    const short* __restrict__ Wkb, const short* __restrict__ Wvb,
    const float2* __restrict__ rope_tab,
    short* __restrict__ Qo, short* __restrict__ Ko, short* __restrict__ Vo)
{
    __shared__ short Ash[128*64];
    __shared__ short Bsh[128*64];

    const int gid = blockIdx.x;
    const int r8  = gid & 7;           // XCD slot (round-robin heuristic)
    const int u   = gid >> 3;          // 0..191
    const int i_idx = r8 * 8 + (u & 7);      // 0..63
    const int nz  = u >> 3;                  // 0..23
    const int n_idx = nz & 7;                // 0..7
    const int z   = nz >> 3;                 // 0..2

    const short* Wm = (z == 0) ? Wqb : ((z == 1) ? Wkb : Wvb);
    const int i0 = i_idx * 128;
    const int n0 = n_idx * 128;

    f32x4 acc[4][4];
    #pragma unroll
    for (int mi = 0; mi < 4; ++mi)
        #pragma unroll
        for (int nj = 0; nj < 4; ++nj) acc[mi][nj] = (f32x4){0.f,0.f,0.f,0.f};

    gemm_bt_128(xb, Wm, Ash, Bsh, i0, n0, acc);

    const int t  = threadIdx.x;
    const int w  = t >> 6;
    const int g  = (t >> 4) & 3;
    const int ln = t & 15;
    const int rh = (w >> 1) * 64;

    if (z == 2) {
        // two passes over heads; buf[64 d][136 seq-stride] spans Ash..Bsh.
        short* buf = Ash;
        const int b = i0 >> 11, l0 = i0 & (LL - 1);
        const int d = t >> 2;
        const int c = t & 3;
        const int dk = d & 7;          // V granule swizzle key
        #pragma unroll
        for (int hp = 0; hp < 2; ++hp) {
            __syncthreads();
            if ((w & 1) == hp) {
                #pragma unroll
                for (int nj = 0; nj < 4; ++nj)
                    #pragma unroll
                    for (int mi = 0; mi < 4; ++mi)
                        #pragma unroll
                        for (int r = 0; r < 4; ++r)
                            buf[(nj*16 + ln)*136 + rh + mi*16 + 4*g + r]
                                = f2bf(acc[mi][nj][r]);
            }
            __syncthreads();
            short* dst = Vo + ((size_t)((b*HH + n_idx*2 + hp)*HD + d)) * LL + l0;
            // permuted + swizzled store: key' granules gi1=2g0+hb, gi2=gi1+2,
            // each XOR'd with d&7 (16-B granule swizzle for attn staging).
            #pragma unroll
            for (int j = 0; j < 4; ++j) {
                const short* src = buf + d*136 + c*8 + j*32;
                bf16x4 lo = *(const bf16x4*)(src);
                bf16x4 hi = *(const bf16x4*)(src + 4);
                const int tb = (j >> 1) * 64;
                const int hb = j & 1;
                const int aa = c >> 1;
                const int g0 = (c & 1) * 2;
                const int gi1 = 2*g0 + hb;
                *(bf16x4*)(dst + tb + ((gi1     ^ dk) << 3) + aa*4) = lo;
                *(bf16x4*)(dst + tb + (((gi1+2) ^ dk) << 3) + aa*4) = hi;
            }
        }
    } else {
        const int h = n_idx * 2 + (w & 1);
        short* Om = (z == 0) ? Qo : Ko;
        // Q: 1/sqrt(64) * log2(e) so scores feed exp2 directly
        const float sc = (z == 0) ? 0.180336880111112f : 1.0f;
        const int gi0 = ln >> 3;
        const int wi  = ln & 7;
        #pragma unroll
        for (int mi = 0; mi < 4; ++mi)
            #pragma unroll
            for (int r = 0; r < 4; ++r) {
                int i = i0 + rh + mi*16 + 4*g + r;
                int b = i >> 11, lq = i & (LL - 1);
                float2 cs0 = rope_tab[lq*32 + ln];        // freq ln
                float2 cs1 = rope_tab[lq*32 + ln + 16];   // freq ln+16
                float r0 = (acc[mi][0][r]*cs0.x - acc[mi][2][r]*cs0.y) * sc;
                float r2 = (acc[mi][2][r]*cs0.x + acc[mi][0][r]*cs0.y) * sc;
                float r1 = (acc[mi][1][r]*cs1.x - acc[mi][3][r]*cs1.y) * sc;
                float r3 = (acc[mi][3][r]*cs1.x + acc[mi][1][r]*cs1.y) * sc;
                size_t base = ((size_t)(b*HH + h) * LL + lq) * HD;
                // K swizzled by lq&7 (== (4g+r)&7); Q linear (xk=0).
                int xk = (z == 0) ? 0 : ((4*g + r) & 7);
                Om[base + (((gi0    ) ^ xk) << 3) + wi] = f2bf(r0);  // col ln
                Om[base + (((gi0 + 2) ^ xk) << 3) + wi] = f2bf(r1);  // col ln+16
                Om[base + (((gi0 + 4) ^ xk) << 3) + wi] = f2bf(r2);  // col ln+32
                Om[base + (((gi0 + 6) ^ xk) << 3) + wi] = f2bf(r3);  // col ln+48
            }
    }
}

// ---------------------------------------------------------------------------
// Kernel 2: bf16 MFMA flash attention (at its structural ceiling:
// MFMA 42% + VALU 50% ~= 92% issue-saturated; MFMA-busy at the
// 16x16-shape floor; 64-VGPR cliff forbids prefetch state).
// grid = (B*H, L/128): bh on x => the 16 q-tile blocks sharing one bh get
// gid == bh (mod 8) -> same XCD -> K/V stay in one L2.
//  (a) l-sum via MFMA ones-trick (lsum element r == O row 4g+r).
//  (b) VT global layout key-bit-permuted -> PV B-frag = one granule read.
//  (c) pk_bf16 = single v_perm_b32.
//  (d) staging via global_load_lds (linear [64][64] LDS; K/VT pre-swizzled
//      in GLOBAL by qkv, reads XOR granule with ln&7).
// ---------------------------------------------------------------------------
__global__ __launch_bounds__(256) void attn_kernel(
    const short* __restrict__ Q, const short* __restrict__ K,
    const short* __restrict__ VT, short* __restrict__ AO)
{
    __shared__ short Ksh[64*64];   // [key][d-granule swizzled]
    __shared__ short VTs[64*64];   // [d][key'-granule swizzled]

    const int t  = threadIdx.x;
    const int w  = t >> 6;
    const int l  = t & 63;
    const int g  = l >> 4;
    const int ln = l & 15;

    const int bh = blockIdx.x;
    const int q0 = blockIdx.y * 128;
    const short* Qb  = Q  + ((size_t)bh * LL + q0 + w*32) * HD;
    const short* Kb  = K  + (size_t)bh * LL * HD;
    const short* VTb = VT + (size_t)bh * HD * LL;

    // Q B-frags: [n=q=ln][k=d=8g+j(+32)] (Q global layout is linear)
    bf16x8 qb[2][2];
    #pragma unroll
    for (int qi = 0; qi < 2; ++qi) {
        qb[qi][0] = *(const bf16x8*)(Qb + (size_t)(qi*16 + ln)*HD + 8*g);
        qb[qi][1] = *(const bf16x8*)(Qb + (size_t)(qi*16 + ln)*HD + 32 + 8*g);
    }

    const bf16x8 ONES = { (short)0x3F80, (short)0x3F80, (short)0x3F80, (short)0x3F80,
                          (short)0x3F80, (short)0x3F80, (short)0x3F80, (short)0x3F80 };

    f32x4 O[2][4];                 // O[qi][db]: row q=4g+r, col d=db*16+ln
    #pragma unroll
    for (int qi = 0; qi < 2; ++qi)
        #pragma unroll
        for (int db = 0; db < 4; ++db) O[qi][db] = (f32x4){0.f,0.f,0.f,0.f};
    f32x4 lsum[2];                 // lsum[qi][r] = l for row q=4g+r (any ln)
    lsum[0] = (f32x4){0.f,0.f,0.f,0.f};
    lsum[1] = (f32x4){0.f,0.f,0.f,0.f};

    // staging geometry: wave w copies rows [w*16, w*16+16) of each 64x64
    // tile; lane l -> row +(l>>3), granule l&7. LDS dest linear.
    const int srow = l >> 3;          // 0..7
    const int scol = (l & 7) * 8;     // granule col (shorts)
    short* kdst = Ksh + w*1024;       // wave-uniform
    short* vdst = VTs + w*1024;
    const int lx = ln & 7;            // read-side XOR key

    for (int kt = 0; kt < LL; kt += 64) {
        __syncthreads();           // previous tile fully consumed
        const short* gk = Kb  + (size_t)(kt + w*16 + srow)*HD + scol;
        const short* gv = VTb + (size_t)(w*16 + srow)*LL + kt + scol;
        gload_lds16(gk,        kdst);
        gload_lds16(gk + 8*HD, kdst + 512);
        gload_lds16(gv,        vdst);
        gload_lds16(gv + 8*LL, vdst + 512);
        __syncthreads();           // auto vmcnt(0) drain -> LDS ready

        unsigned pf[2][4][2];      // [qi][kb]: keys (4g,4g+1),(4g+2,4g+3)
        #pragma unroll
        for (int kb = 0; kb < 4; ++kb) {
            // K A-frags: [m=key=kb*16+ln][k=d], granules g and g+4, XOR lx
            bf16x8 ka0 = *(const bf16x8*)(Ksh + (kb*16 + ln)*64 + ((g       ^ lx) << 3));
            bf16x8 ka1 = *(const bf16x8*)(Ksh + (kb*16 + ln)*64 + (((g + 4) ^ lx) << 3));
            #pragma unroll
            for (int qi = 0; qi < 2; ++qi) {
                f32x4 Sv = (f32x4){0.f,0.f,0.f,0.f};
                Sv = __builtin_amdgcn_mfma_f32_16x16x32_bf16(ka0, qb[qi][0], Sv, 0, 0, 0);
                Sv = __builtin_amdgcn_mfma_f32_16x16x32_bf16(ka1, qb[qi][1], Sv, 0, 0, 0);
                float p0 = exp2x(Sv[0]), p1 = exp2x(Sv[1]);
                float p2 = exp2x(Sv[2]), p3 = exp2x(Sv[3]);
                pf[qi][kb][0] = pk_bf16(p0, p1);
                pf[qi][kb][1] = pk_bf16(p2, p3);
            }
        }

        // P A-frags for PV/lsum: slot (g,j) <-> key 32hb + 16*(j>>2) + 4g + (j&3)
        bf16x8 pa[2][2];
        #pragma unroll
        for (int qi = 0; qi < 2; ++qi)
            #pragma unroll
            for (int hb = 0; hb < 2; ++hb) {
                union { unsigned u[4]; bf16x8 v; } a;
                a.u[0] = pf[qi][2*hb][0];   a.u[1] = pf[qi][2*hb][1];
                a.u[2] = pf[qi][2*hb+1][0]; a.u[3] = pf[qi][2*hb+1][1];
                pa[qi][hb] = a.v;
            }

        // l-sum: one MFMA per (hb,qi) with all-ones B
        #pragma unroll
        for (int hb = 0; hb < 2; ++hb) {
            lsum[0] = __builtin_amdgcn_mfma_f32_16x16x32_bf16(pa[0][hb], ONES, lsum[0], 0, 0, 0);
            lsum[1] = __builtin_amdgcn_mfma_f32_16x16x32_bf16(pa[1][hb], ONES, lsum[1], 0, 0, 0);
        }

        // PV via 16x16x32: B-frag = granule (2g+hb) ^ lx of row db*16+ln
        #pragma unroll
        for (int hb = 0; hb < 2; ++hb) {
            #pragma unroll
            for (int db = 0; db < 4; ++db) {
                bf16x8 vf = *(const bf16x8*)(VTs + (db*16 + ln)*64 + (((2*g + hb) ^ lx) << 3));
                O[0][db] = __builtin_amdgcn_mfma_f32_16x16x32_bf16(pa[0][hb], vf, O[0][db], 0, 0, 0);
                O[1][db] = __builtin_amdgcn_mfma_f32_16x16x32_bf16(pa[1][hb], vf, O[1][db], 0, 0, 0);
            }
        }
    }

    // epilogue: lsum[qi][r] is exactly l for row q=4g+r — no shuffles.
    const int b = bh >> 4, h = bh & 15;
    #pragma unroll
    for (int qi = 0; qi < 2; ++qi) {
        #pragma unroll
        for (int r = 0; r < 4; ++r) {
            float inv = 1.0f / lsum[qi][r];
            int q = q0 + w*32 + qi*16 + 4*g + r;
            size_t base = ((size_t)(b*LL + q)) * DD + h*HD;
            #pragma unroll
            for (int db = 0; db < 4; ++db)
                AO[base + db*16 + ln] = f2bf(O[qi][db][r] * inv);
        }
    }
}

// ---------------------------------------------------------------------------
// Kernel 3: output projection. 1-D grid 512, same XCD-aware decode as qkv:
// each XCD owns 8 i-tiles of A + iterates the 8 Wo n-tiles.
// ---------------------------------------------------------------------------
__global__ __launch_bounds__(256, 4) void oproj_mfma_kernel(
    const short* __restrict__ A, const short* __restrict__ Wob,
    float* __restrict__ out)
{
    __shared__ short Ash[128*64];
    __shared__ short Bsh[128*64];

    const int gid = blockIdx.x;
    const int r8  = gid & 7;
    const int u   = gid >> 3;              // 0..63
    const int i_idx = r8 * 8 + (u & 7);    // 0..63
    const int n_idx = u >> 3;              // 0..7
    const int i0 = i_idx * 128;
    const int n0 = n_idx * 128;

    f32x4 acc[4][4];
    #pragma unroll
    for (int mi = 0; mi < 4; ++mi)
        #pragma unroll
        for (int nj = 0; nj < 4; ++nj) acc[mi][nj] = (f32x4){0.f,0.f,0.f,0.f};

    gemm_bt_128(A, Wob, Ash, Bsh, i0, n0, acc);

    const int t  = threadIdx.x;
    const int w  = t >> 6;
    const int g  = (t >> 4) & 3;
    const int ln = t & 15;
    const int rh = (w >> 1) * 64;
    const int ch = (w & 1) * 64;

    #pragma unroll
    for (int mi = 0; mi < 4; ++mi)
        #pragma unroll
        for (int r = 0; r < 4; ++r) {
            size_t base = (size_t)(i0 + rh + mi*16 + 4*g + r) * DD + n0 + ch;
            #pragma unroll
            for (int nj = 0; nj < 4; ++nj)
                out[base + nj*16 + ln] = acc[mi][nj][r];
        }
}

// ---------------------------------------------------------------------------
extern "C" void kernel_launch(void* const* d_in, const int* in_sizes, int n_in,
                              void* d_out, int out_size, void* d_ws, size_t ws_size,
                              hipStream_t stream) {
    const float* x  = (const float*)d_in[0];
    const float* Wq = (const float*)d_in[1];
    const float* Wk = (const float*)d_in[2];
    const float* Wv = (const float*)d_in[3];
    const float* Wo = (const float*)d_in[4];
    float* out = (float*)d_out;

    const size_t n_x = (size_t)BL * DD;   // 8.4M
    const size_t n_w = (size_t)DD * DD;   // 1.05M
    short* xb  = (short*)d_ws;
    short* Wqb = xb  + n_x;               // Wqb..Wob contiguous (prep relies on it)
    short* Wkb = Wqb + n_w;
    short* Wvb = Wkb + n_w;
    short* Wob = Wvb + n_w;
    short* Q   = Wob + n_w;
    short* K   = Q   + n_x;               // granule-swizzled by token&7
    short* VTg = K   + n_x;               // V transposed, key-permuted + swizzled
    short* AOb = VTg + n_x;
    float2* tab = (float2*)(AOb + n_x);   // 65536 float2 = 512 KB

    prep_kernel<<<NB_CASTX + NB_CASTW + NB_ROPE, 256, 0, stream>>>(
        x, Wq, Wk, Wv, Wo, xb, Wqb, tab);

    qkv_mfma_kernel<<<1536, 256, 0, stream>>>(xb, Wqb, Wkb, Wvb, tab, Q, K, VTg);

    dim3 g2(BB*HH, LL/128);
    attn_kernel<<<g2, 256, 0, stream>>>(Q, K, VTg, AOb);

    oproj_mfma_kernel<<<512, 256, 0, stream>>>(AOb, Wob, out);
}